// Round 7
// baseline (387.532 us; speedup 1.0000x reference)
//
#include <hip/hip_runtime.h>
#include <hip/hip_bf16.h>
#include <math.h>

// Problem constants (B=16, N=1024, D=256, F=1024, H=8, hd=32)
#define Bq 16
#define Nq 1024
#define Dq 256
#define Fq 1024
#define Hq 8
#define HDq 32
#define Mq (Bq * Nq)          // 16384 rows
#define SCALE 0.0625f          // D^-0.5 = 1/16
#define LN_EPS 1e-5f

typedef __attribute__((ext_vector_type(8))) short short8;   // 8 bf16
typedef __attribute__((ext_vector_type(4))) float f32x4;

__device__ __forceinline__ float bf2f(unsigned short s) {
    unsigned u = ((unsigned)s) << 16;
    return __builtin_bit_cast(float, u);
}
__device__ __forceinline__ unsigned short f2bf(float f) {
    __hip_bfloat16 h = __float2bfloat16(f);
    return __builtin_bit_cast(unsigned short, h);
}

// async global->LDS, 16B per lane (lands at ldsbase + lane*16)
typedef __attribute__((address_space(3))) unsigned int lds_uint;
typedef const __attribute__((address_space(1))) unsigned int glb_uint;
__device__ __forceinline__ void async16(void* lds, const void* g) {
    __builtin_amdgcn_global_load_lds((glb_uint*)g, (lds_uint*)lds, 16, 0, 0);
}

__device__ __forceinline__ float gelu_tanh(float v) {
    const float c = 0.7978845608028654f;
    float u = c * (v + 0.044715f * v * v * v);
    return 0.5f * v * (1.0f + tanhf(u));
}

// ---------------------------------------------------------------------------
// Kernel 0: convert the 6 weight matrices to bf16 (Wq,Wk,Wv rows 0..767 of W16)
// ---------------------------------------------------------------------------
__global__ __launch_bounds__(256) void cvt_weights(
    const float* __restrict__ Wq, const float* __restrict__ Wk,
    const float* __restrict__ Wv, const float* __restrict__ Wo,
    const float* __restrict__ W1, const float* __restrict__ W2,
    unsigned short* __restrict__ dst)
{
    const int blk = blockIdx.x;
    int seg, local;
    if (blk < 256)      { seg = blk >> 6; local = blk & 63; }
    else if (blk < 512) { seg = 4; local = blk - 256; }
    else                { seg = 5; local = blk - 512; }
    const float* srcs[6] = {Wq, Wk, Wv, Wo, W1, W2};
    const size_t dsto[6] = {0, 65536, 131072, 196608, 262144, 524288};
    const float* src = srcs[seg] + (size_t)local * 1024;
    unsigned short* d = dst + dsto[seg] + (size_t)local * 1024;
    const int t4 = threadIdx.x * 4;
    float4 v = *(const float4*)(src + t4);
    uint2 o;
    o.x = (unsigned)f2bf(v.x) | ((unsigned)f2bf(v.y) << 16);
    o.y = (unsigned)f2bf(v.z) | ((unsigned)f2bf(v.w) << 16);
    *(uint2*)(d + t4) = o;
}

// ---------------------------------------------------------------------------
// Kernel 0b: bias16 = bf16(sp + ed), ROW-MAJOR, pure streaming.
// The swapped-operand attn consumes row-major bias directly (uint2/lane), so
// no transpose/permute pass is needed at all.
// ---------------------------------------------------------------------------
__global__ __launch_bounds__(256) void bias_cvt(
    const float* __restrict__ sp, const float* __restrict__ ed,
    unsigned short* __restrict__ dst)
{
    const size_t i = ((size_t)blockIdx.x * 256 + threadIdx.x) * 8;
    float4 a0 = *(const float4*)(sp + i);
    float4 a1 = *(const float4*)(sp + i + 4);
    float4 e0 = *(const float4*)(ed + i);
    float4 e1 = *(const float4*)(ed + i + 4);
    uint4 o;
    o.x = (unsigned)f2bf(a0.x + e0.x) | ((unsigned)f2bf(a0.y + e0.y) << 16);
    o.y = (unsigned)f2bf(a0.z + e0.z) | ((unsigned)f2bf(a0.w + e0.w) << 16);
    o.z = (unsigned)f2bf(a1.x + e1.x) | ((unsigned)f2bf(a1.y + e1.y) << 16);
    o.w = (unsigned)f2bf(a1.z + e1.z) | ((unsigned)f2bf(a1.w + e1.w) << 16);
    *(uint4*)(dst + i) = o;
}

// ---------------------------------------------------------------------------
// Kernel 1: fused double LayerNorm -> bf16 outputs (shared mean/rstd)
// ---------------------------------------------------------------------------
__global__ __launch_bounds__(256) void ln2_kernel(
    const float* __restrict__ x,
    const float* __restrict__ g1, const float* __restrict__ bb1,
    const float* __restrict__ g2, const float* __restrict__ bb2,
    unsigned short* __restrict__ att_in, unsigned short* __restrict__ ffn_in)
{
    const int row = blockIdx.x;
    const int t = threadIdx.x;
    const size_t base = (size_t)row * Dq;
    float v = x[base + t];

    float s = v, sq = v * v;
    #pragma unroll
    for (int off = 32; off > 0; off >>= 1) {
        s  += __shfl_down(s, off);
        sq += __shfl_down(sq, off);
    }
    __shared__ float ssum[4], ssq[4];
    __shared__ float mu_s, rstd_s;
    const int lane = t & 63, wid = t >> 6;
    if (lane == 0) { ssum[wid] = s; ssq[wid] = sq; }
    __syncthreads();
    if (t == 0) {
        float S = ssum[0] + ssum[1] + ssum[2] + ssum[3];
        float Q = ssq[0] + ssq[1] + ssq[2] + ssq[3];
        float mu = S * (1.0f / Dq);
        float var = Q * (1.0f / Dq) - mu * mu;
        mu_s = mu;
        rstd_s = rsqrtf(var + LN_EPS);
    }
    __syncthreads();
    const float nx = (v - mu_s) * rstd_s;
    att_in[base + t] = f2bf(nx * g1[t] + bb1[t]);
    ffn_in[base + t] = f2bf(nx * g2[t] + bb2[t]);
}

// ---------------------------------------------------------------------------
// Kernel 2: MFMA NT GEMM  C[M,Nc] = A[M,K] * W[Nc,K]^T  (bf16 in, fp32 acc)
// 128x128 tile, BK=32, double-buffered prefetch.
// mode 0: fp32 out (+bias,+gelu,+add) [Wo, FFN2]; flagW: atomicOr per-row
//         any-zero flag (pad_mask2 producer); flagR: zero flagged rows.
// mode 1: bf16 flat out (+bias,+gelu)   [FFN1]
// mode 2: merged QKV (Nc=768): Q scaled+head-major, K head-major, V transposed
// ---------------------------------------------------------------------------
#define TM 128
#define TN 128
#define TK 32

__global__ __launch_bounds__(256) void gemm_mfma(
    const unsigned short* __restrict__ A, const unsigned short* __restrict__ W,
    const float* __restrict__ bias, const float* __restrict__ add,
    float* __restrict__ outF, unsigned short* __restrict__ outBF,
    unsigned short* __restrict__ Qb, unsigned short* __restrict__ Kb,
    unsigned short* __restrict__ Vt,
    int M, int Nc, int K, int mode, int apply_gelu,
    unsigned* __restrict__ flagW, const unsigned* __restrict__ flagR)
{
    __shared__ unsigned short As[2][TM * TK];   // 2 x 8 KB
    __shared__ unsigned short Bs[2][TN * TK];   // 2 x 8 KB
    const int t = threadIdx.x;
    const int w = t >> 6, lane = t & 63;
    const int col = lane & 15, quad = lane >> 4;
    const int wr = w >> 1, wc = w & 1;
    const int row0 = blockIdx.y * TM;
    const int col0 = blockIdx.x * TN;

    f32x4 acc[4][4] = {};

    // per-thread staging geometry (wave-uniform LDS base; lane scatters x16B)
    const int c0s = w * 128 + lane;          // chunk for j=0
    const int c1s = c0s + 64;                // chunk for j=1
    const int r0s = c0s >> 2, s0s = (c0s & 3) * 8;
    const int r1s = c1s >> 2, s1s = (c1s & 3) * 8;

#define STAGE(buf, kk)                                                        \
    do {                                                                      \
        async16(&As[buf][(w * 128) * 8],      A + (size_t)(row0 + r0s) * K + (kk) + s0s); \
        async16(&Bs[buf][(w * 128) * 8],      W + (size_t)(col0 + r0s) * K + (kk) + s0s); \
        async16(&As[buf][(w * 128 + 64) * 8], A + (size_t)(row0 + r1s) * K + (kk) + s1s); \
        async16(&Bs[buf][(w * 128 + 64) * 8], W + (size_t)(col0 + r1s) * K + (kk) + s1s); \
    } while (0)

    STAGE(0, 0);
    __syncthreads();   // buf0 staged

    int cur = 0;
    for (int k0 = 0; k0 < K; k0 += TK) {
        if (k0 + TK < K) STAGE(cur ^ 1, k0 + TK);   // prefetch next (async)
        short8 wf[4], af[4];
        #pragma unroll
        for (int i = 0; i < 4; i++)
            wf[i] = *(const short8*)&Bs[cur][(wc * 64 + i * 16 + col) * TK + quad * 8];
        #pragma unroll
        for (int j = 0; j < 4; j++)
            af[j] = *(const short8*)&As[cur][(wr * 64 + j * 16 + col) * TK + quad * 8];
        // D[c][r]: A-operand = W rows (c), B-operand = A rows (r)
        #pragma unroll
        for (int i = 0; i < 4; i++)
            #pragma unroll
            for (int j = 0; j < 4; j++)
                acc[i][j] = __builtin_amdgcn_mfma_f32_16x16x32_bf16(wf[i], af[j], acc[i][j], 0, 0, 0);
        __syncthreads();   // drains prefetch (vmcnt) + frag reads; swap safe
        cur ^= 1;
    }
#undef STAGE

    // epilogue: lane owns cols c0..c0+3 (consecutive), output row r
    #pragma unroll
    for (int i = 0; i < 4; i++) {
        #pragma unroll
        for (int j = 0; j < 4; j++) {
            const int c0 = col0 + wc * 64 + i * 16 + quad * 4;
            const int r  = row0 + wr * 64 + j * 16 + col;
            float4 v = make_float4(acc[i][j][0], acc[i][j][1], acc[i][j][2], acc[i][j][3]);
            if (mode == 2 && c0 < 256) { v.x *= SCALE; v.y *= SCALE; v.z *= SCALE; v.w *= SCALE; }
            if (bias) {
                float4 bb = *(const float4*)&bias[c0];
                v.x += bb.x; v.y += bb.y; v.z += bb.z; v.w += bb.w;
            }
            if (apply_gelu) {
                v.x = gelu_tanh(v.x); v.y = gelu_tanh(v.y);
                v.z = gelu_tanh(v.z); v.w = gelu_tanh(v.w);
            }
            if (add) {
                float4 aa = *(const float4*)&add[(size_t)r * Nc + c0];
                v.x += aa.x; v.y += aa.y; v.z += aa.z; v.w += aa.w;
            }
            if (mode == 0) {
                if (flagR && flagR[r]) { v.x = 0.f; v.y = 0.f; v.z = 0.f; v.w = 0.f; }
                if (flagW && ((v.x == 0.f) || (v.y == 0.f) || (v.z == 0.f) || (v.w == 0.f)))
                    atomicOr(&flagW[r], 1u);
                *(float4*)&outF[(size_t)r * Nc + c0] = v;
            } else if (mode == 1) {
                uint2 o;
                o.x = (unsigned)f2bf(v.x) | ((unsigned)f2bf(v.y) << 16);
                o.y = (unsigned)f2bf(v.z) | ((unsigned)f2bf(v.w) << 16);
                *(uint2*)&outBF[(size_t)r * Nc + c0] = o;
            } else {
                const int b = r >> 10, n = r & 1023;
                if (c0 < 512) {
                    // Q (c0<256, pre-scaled) or K: head-major [B,H,N,32]
                    const int cq = c0 & 255;
                    const int h = cq >> 5, d0 = cq & 31;
                    unsigned short* dst = (c0 < 256 ? Qb : Kb);
                    uint2 o;
                    o.x = (unsigned)f2bf(v.x) | ((unsigned)f2bf(v.y) << 16);
                    o.y = (unsigned)f2bf(v.z) | ((unsigned)f2bf(v.w) << 16);
                    *(uint2*)&dst[(((size_t)(b * Hq + h) << 10) + n) * HDq + d0] = o;
                } else {
                    // V transposed: Vt[B,H,32,N]
                    const int cv = c0 - 512;
                    const int h = cv >> 5, d0 = cv & 31;
                    unsigned short* dst = Vt + (((size_t)(b * Hq + h) * HDq + d0) << 10) + n;
                    dst[0]      = f2bf(v.x);
                    dst[1024]   = f2bf(v.y);
                    dst[2048]   = f2bf(v.z);
                    dst[3072]   = f2bf(v.w);
                }
            }
        }
    }
}

// ---------------------------------------------------------------------------
// Kernel 3: MFMA attention, K/V LDS-resident, 16 waves, SWAPPED QK^T operands.
// mfma(K_frag, Q_frag) puts the C-fragment as S^T: lane (quad,col) holds
// q-row=col, keys=m0+quad*4..+3 -> 4 CONSECUTIVE keys. Consequences:
//   * bias = ONE uint2 load per fragment from ROW-MAJOR bias16 (no permute
//     kernel, no transpose anywhere);
//   * S-store = ONE swizzled uint2 write (was 4 scattered u16);
//   * row-sum = scalar per lane + shfl_xor(16/32) + shfl broadcast at end.
// Block = (b, h, nh): 256 blocks (1/CU), 1024 thr = 16 waves, 2 q-tiles/wave.
// K (64KB) + V (64KB) staged once via global_load_lds; S 16x2KB -> 160KB LDS.
// XCD map: xg=flat&7 gets (b,nh) pairs {4xg..4xg+3} x 8 heads, so the 8 head-
// blocks sharing a 1MB bias slice sit on ONE XCD's L2 (4MB working set).
// Swizzles (XOR involutions; K/V staged via pre-swizzled global source):
//   K u16 idx ^= ((idx>>6)&3)<<3, V u16 idx ^= ((idx>>10)&7)<<3,
//   S u16 idx ^= (col&7)<<3 on write AND read (b128 reads conflict-free).
// Also zeroes the pad-flags buffer for the downstream Wo gemm.
// ---------------------------------------------------------------------------
__global__ __launch_bounds__(1024, 4) void attn_mfma(
    const unsigned short* __restrict__ Qbf, const unsigned short* __restrict__ Kbf,
    const unsigned short* __restrict__ Vt, const unsigned short* __restrict__ bias16,
    unsigned short* __restrict__ O16, unsigned* __restrict__ flags)
{
    const int flat = blockIdx.x;
    const int xg = flat & 7;                  // XCD (round-robin dispatch)
    const int jj = flat >> 3;                 // 0..31 within XCD
    const int pair = xg * 4 + (jj >> 3);      // (b,nh) pair 0..31
    const int b  = pair >> 1;
    const int nh = pair & 1;
    const int h  = jj & 7;

    const int t = threadIdx.x;
    const int w = t >> 6;            // wave 0..15
    const int lane = t & 63;
    const int col = lane & 15;
    const int quad = lane >> 4;

    if (t < 64) flags[flat * 64 + t] = 0;   // zero pad-flags (dead QKV-W region)

    __shared__ unsigned short Klds[32768];     // 64 KB  [1024][32] swizzled
    __shared__ unsigned short Vlds[32768];     // 64 KB  [32][1024] swizzled
    __shared__ unsigned short S16[16][1024];   // 32 KB, 2 KB per wave

    const size_t hb = (size_t)b * Hq + h;
    const unsigned short* Qh = Qbf + hb * (Nq * HDq);
    const unsigned short* Kh = Kbf + hb * (Nq * HDq);
    const unsigned short* Vh = Vt  + hb * (HDq * Nq);

    // ---- stage K,V -> LDS (linear dest, inverse-swizzled source)
    #pragma unroll
    for (int i = 0; i < 4; i++) {
        const int ck = i * 1024 + t;                   // 16B chunk id, 0..4095
        async16(&Klds[ck * 8], Kh + ((ck * 8) ^ (((ck >> 3) & 3) << 3)));
        async16(&Vlds[ck * 8], Vh + ((ck * 8) ^ (((ck >> 7) & 7) << 3)));
    }

    // ---- Q rows for my 2 q-tiles (independent of staging)
    const int n0 = nh * 512 + w * 32;
    short8 aq[2];
    #pragma unroll
    for (int qt = 0; qt < 2; qt++)
        aq[qt] = *(const short8*)(Qh + (size_t)(n0 + qt * 16 + col) * HDq + quad * 8);

    const unsigned short* bg = bias16 + ((size_t)b * Nq + n0) * Nq;  // rows n0..
    unsigned short* Sw = &S16[w][0];

    __syncthreads();   // staging complete — the only barrier

    f32x4 o0[2] = {{0.f,0.f,0.f,0.f},{0.f,0.f,0.f,0.f}};
    f32x4 o1[2] = {{0.f,0.f,0.f,0.f},{0.f,0.f,0.f,0.f}};
    float rsum[2] = {0.f, 0.f};

    for (int tt = 0; tt < 16; tt++) {                  // 64-key tiles
        const int k0 = tt * 64;
        // K/V fragments for this tile: shared by both q-tiles
        short8 kf[4], vf0[2], vf1[2];
        #pragma unroll
        for (int m = 0; m < 4; m++)
            kf[m] = *(const short8*)&Klds[((k0 + m * 16 + col) * 32 + quad * 8)
                                          ^ (((col >> 1) & 3) << 3)];
        #pragma unroll
        for (int c = 0; c < 2; c++) {
            vf0[c] = *(const short8*)&Vlds[((col << 10) + k0 + c * 32 + quad * 8)
                                           ^ ((col & 7) << 3)];
            vf1[c] = *(const short8*)&Vlds[(((col + 16) << 10) + k0 + c * 32 + quad * 8)
                                           ^ ((col & 7) << 3)];
        }
        #pragma unroll
        for (int qt = 0; qt < 2; qt++) {
            const unsigned short* bq = bg + (size_t)(qt * 16 + col) * Nq + k0;
            // ---- QK^T (swapped: S^T fragment) + bias + exp -> S-tile
            #pragma unroll
            for (int m = 0; m < 4; m++) {
                f32x4 cc = {0.f, 0.f, 0.f, 0.f};
                cc = __builtin_amdgcn_mfma_f32_16x16x32_bf16(kf[m], aq[qt], cc, 0, 0, 0);
                uint2 bv = *(const uint2*)(bq + m * 16 + quad * 4);
                const float e0 = __expf(cc[0] + bf2f((unsigned short)(bv.x & 0xffff)));
                const float e1 = __expf(cc[1] + bf2f((unsigned short)(bv.x >> 16)));
                const float e2 = __expf(cc[2] + bf2f((unsigned short)(bv.y & 0xffff)));
                const float e3 = __expf(cc[3] + bf2f((unsigned short)(bv.y >> 16)));
                rsum[qt] += (e0 + e1) + (e2 + e3);
                uint2 sv;
                sv.x = (unsigned)f2bf(e0) | ((unsigned)f2bf(e1) << 16);
                sv.y = (unsigned)f2bf(e2) | ((unsigned)f2bf(e3) << 16);
                const int widx = (col * 64 + m * 16 + quad * 4) ^ ((col & 7) << 3);
                *(uint2*)&Sw[widx] = sv;
            }
            // ---- PV: S-tile @ V (same-wave LDS RAW; compiler inserts waits)
            #pragma unroll
            for (int c = 0; c < 2; c++) {
                const int ridx = (col * 64 + c * 32 + quad * 8) ^ ((col & 7) << 3);
                short8 ap = *(const short8*)&Sw[ridx];
                o0[qt] = __builtin_amdgcn_mfma_f32_16x16x32_bf16(ap, vf0[c], o0[qt], 0, 0, 0);
                o1[qt] = __builtin_amdgcn_mfma_f32_16x16x32_bf16(ap, vf1[c], o1[qt], 0, 0, 0);
            }
        }
    }

    // ---- rsum[qt] holds partial sum for q-row `col` (this lane's quads+tiles)
    //      reduce across the 4 quads (lanes col, col+16, col+32, col+48)
    #pragma unroll
    for (int qt = 0; qt < 2; qt++) {
        rsum[qt] += __shfl_xor(rsum[qt], 16);
        rsum[qt] += __shfl_xor(rsum[qt], 32);
    }

    // ---- normalize + store: O fragment row = quad*4+i, col = d; fetch the
    //      row-sum for q=quad*4+i from lane col=quad*4+i via shfl(width 16)
    #pragma unroll
    for (int qt = 0; qt < 2; qt++) {
        unsigned short* op = O16 + ((size_t)b * Nq + n0 + qt * 16) * Dq + h * HDq;
        #pragma unroll
        for (int i = 0; i < 4; i++) {
            const float inv = 1.0f / __shfl(rsum[qt], quad * 4 + i, 16);
            const int q = quad * 4 + i;
            op[(size_t)q * Dq + col]      = f2bf(o0[qt][i] * inv);
            op[(size_t)q * Dq + col + 16] = f2bf(o1[qt][i] * inv);
        }
    }
}

// ---------------------------------------------------------------------------
extern "C" void kernel_launch(void* const* d_in, const int* in_sizes, int n_in,
                              void* d_out, int out_size, void* d_ws, size_t ws_size,
                              hipStream_t stream)
{
    const float* x      = (const float*)d_in[0];
    const float* sp     = (const float*)d_in[1];
    const float* ed     = (const float*)d_in[2];
    const float* gamma1 = (const float*)d_in[3];
    const float* beta1  = (const float*)d_in[4];
    const float* gamma2 = (const float*)d_in[5];
    const float* beta2  = (const float*)d_in[6];
    const float* Wq     = (const float*)d_in[7];
    const float* Wk     = (const float*)d_in[8];
    const float* Wv     = (const float*)d_in[9];
    const float* Wo     = (const float*)d_in[10];
    const float* W1     = (const float*)d_in[11];
    const float* b1     = (const float*)d_in[12];
    const float* W2     = (const float*)d_in[13];
    const float* b2     = (const float*)d_in[14];
    float* out = (float*)d_out;

    // workspace layout (in shorts)
    unsigned short* s = (unsigned short*)d_ws;
    const size_t MD = (size_t)Mq * Dq;                  // 4.19M elements
    unsigned short* att_in16 = s;                        // [M,D] bf16; reused as O16
    unsigned short* ffn_in16 = s + MD;                   // [M,D] bf16
    unsigned short* Qbf      = s + 2 * MD;               // [B,H,N,32] bf16
    unsigned short* Kbf      = s + 3 * MD;               // [B,H,N,32] bf16
    unsigned short* Vtb      = s + 4 * MD;               // [B,H,32,N] bf16 (transposed)
    unsigned short* W16      = s + 5 * MD;               // 786432 shorts
    unsigned short* h16      = s + 5 * MD + 786432;      // [M,F] bf16 (33.5 MB)
    unsigned short* O16      = att_in16;                 // attn out (att_in dead)
    float*          AO       = (float*)Qbf;              // [M,D] fp32 (Q/K dead)
    // bias16 [B,N,N] bf16 = 16.78M shorts == exactly h16's size; bias16 is
    // dead before FFN1 writes h16 -> alias them (no extra workspace).
    unsigned short* bias16   = h16;
    // pad-mask flags: 16384 uints = 64 KB, aliases the Wq/Wk/Wv bf16 region
    // (dead after the QKV gemm; zeroed by attn; Wo writes; FFN2 reads).
    unsigned*       flags    = (unsigned*)W16;

    unsigned short* Wo16 = W16 + 196608;
    unsigned short* W116 = W16 + 262144;
    unsigned short* W216 = W16 + 524288;

    // 0) weights -> bf16 (Wq/Wk/Wv contiguous as rows 0..767 for merged QKV)
    cvt_weights<<<768, 256, 0, stream>>>(Wq, Wk, Wv, Wo, W1, W2, W16);

    // 0b) bias16 = bf16(sp + ed), row-major streaming
    bias_cvt<<<8192, 256, 0, stream>>>(sp, ed, bias16);

    // 1) both layernorms -> bf16
    ln2_kernel<<<Mq, 256, 0, stream>>>(x, gamma1, beta1, gamma2, beta2, att_in16, ffn_in16);

    // 2) merged QKV projection (Q scaled + head-major, K head-major, V transposed)
    dim3 gQKV(768 / TN, Mq / TM);   // (6, 128)
    gemm_mfma<<<gQKV, 256, 0, stream>>>(att_in16, W16, nullptr, nullptr, nullptr, nullptr,
                                        Qbf, Kbf, Vtb, Mq, 768, Dq, 2, 0, nullptr, nullptr);

    // 3) attention: 256 blocks = (b, h, nh), K/V LDS-resident, swapped QK^T
    attn_mfma<<<256, 1024, 0, stream>>>(Qbf, Kbf, Vtb, bias16, O16, flags);

    // 4) output projection + residual: AO = O @ Wo^T + x  (+pad-flag produce)
    dim3 gP(Dq / TN, Mq / TM);
    gemm_mfma<<<gP, 256, 0, stream>>>(O16, Wo16, nullptr, x, AO, nullptr,
                                      nullptr, nullptr, nullptr, Mq, Dq, Dq, 0, 0,
                                      flags, nullptr);

    // 5) FFN1: h16 = bf16(gelu(ffn_in @ W1^T + b1))
    dim3 gF1(Fq / TN, Mq / TM);
    gemm_mfma<<<gF1, 256, 0, stream>>>(ffn_in16, W116, b1, nullptr, nullptr, h16,
                                       nullptr, nullptr, nullptr, Mq, Fq, Dq, 1, 1,
                                       nullptr, nullptr);

    // 6) FFN2: out = h @ W2^T + b2 + AO, zeroing pad-flagged rows (pad2 fused)
    gemm_mfma<<<gP, 256, 0, stream>>>(h16, W216, b2, AO, out, nullptr,
                                      nullptr, nullptr, nullptr, Mq, Dq, Fq, 0, 0,
                                      nullptr, flags);
}